// Round 4
// baseline (107.454 us; speedup 1.0000x reference)
//
#include <hip/hip_runtime.h>
#include <hip/hip_bf16.h>

// EmbeddingShard: out[t, :] = (W_full[tok[t], :] + sum_s b[s, :]) / SHARDS
// x: [16384] int32; W_full: [50400, 4096] f32; b: [8, 4096] f32;
// out: [16384, 4096] f32. ~537 MB HBM traffic, memory-bound.
//
// R2 lesson: nt stores diverge post-timing (L2-coherence vs readback) — banned.
// R3 lesson: 1-token/block == 4-token/block (106 us) -> schedule-insensitive,
//            so attack launch overhead (fuse bias kernel) + read/write decoupling.

#define D_MODEL 4096
#define SHARDS 8
#define TPB 8  // tokens per block

typedef float f32x4 __attribute__((ext_vector_type(4)));

// Single fused kernel. 2048 blocks x 256 threads, 8 tokens each.
// Per block: bias summed from b (L2-resident 128 KB) into registers once,
// then a 2-deep pipeline over tokens: prefetch row i+1 while storing row i.
__global__ __launch_bounds__(256) void fused_gather_kernel(const int* __restrict__ tok,
                                                           const float* __restrict__ W,
                                                           const float* __restrict__ b,
                                                           float* __restrict__ out,
                                                           int ntok) {
    const int tid = threadIdx.x;
    const int base = blockIdx.x * TPB;

    // Per-thread bias fragment: bias[j] = sum_s b[s][tid + j*256] (unscaled;
    // epilogue does (w + bias) * 0.125f — exact /8, matches reference order).
    f32x4 bias[4];
#pragma unroll
    for (int j = 0; j < 4; ++j) {
        f32x4 s = {0.f, 0.f, 0.f, 0.f};
#pragma unroll
        for (int sh = 0; sh < SHARDS; ++sh)
            s += reinterpret_cast<const f32x4*>(b + sh * D_MODEL)[tid + j * 256];
        bias[j] = s;
    }

    const f32x4* W4   = reinterpret_cast<const f32x4*>(W);
    f32x4*       out4 = reinterpret_cast<f32x4*>(out);

    // Prologue: load token 0's row.
    int row = tok[base];  // block-uniform -> scalar load
    f32x4 cur[4];
    {
        const f32x4* wr = W4 + (size_t)row * (D_MODEL / 4);
#pragma unroll
        for (int j = 0; j < 4; ++j) cur[j] = wr[tid + j * 256];
    }

#pragma unroll 1  // keep the 2-deep pipeline; full unroll would balloon VGPRs
    for (int i = 0; i < TPB; ++i) {
        f32x4 nxt[4];
        const bool have_next = (i + 1 < TPB) && (base + i + 1 < ntok);
        if (have_next) {
            const int nrow = tok[base + i + 1];           // scalar load, 1 iter of lead
            const f32x4* wn = W4 + (size_t)nrow * (D_MODEL / 4);
#pragma unroll
            for (int j = 0; j < 4; ++j) nxt[j] = wn[tid + j * 256];  // issue early
        }
        if (base + i < ntok) {
            f32x4* orow = out4 + (size_t)(base + i) * (D_MODEL / 4);
#pragma unroll
            for (int j = 0; j < 4; ++j) orow[tid + j * 256] = (cur[j] + bias[j]) * 0.125f;
        }
        if (have_next) {
#pragma unroll
            for (int j = 0; j < 4; ++j) cur[j] = nxt[j];
        }
    }
}

extern "C" void kernel_launch(void* const* d_in, const int* in_sizes, int n_in,
                              void* d_out, int out_size, void* d_ws, size_t ws_size,
                              hipStream_t stream) {
    const int*   tok = (const int*)d_in[0];     // [16384]
    const float* W   = (const float*)d_in[1];   // [50400, 4096]
    const float* b   = (const float*)d_in[2];   // [8, 4096]
    float*       out = (float*)d_out;           // [16384, 4096]

    const int ntok = in_sizes[0];               // 16384
    const int grid = (ntok + TPB - 1) / TPB;    // 2048

    fused_gather_kernel<<<grid, 256, 0, stream>>>(tok, W, b, out, ntok);
}

// Round 5
// 89.089 us; speedup vs baseline: 1.2061x; 1.2061x over previous
//
#include <hip/hip_runtime.h>
#include <hip/hip_bf16.h>

// EmbeddingShard: out[t, :] = (W_full[tok[t], :] + sum_s b[s, :]) / SHARDS
// x: [16384] int32; W_full: [50400, 4096] f32; b: [8, 4096] f32;
// out: [16384, 4096] f32. ~537 MB HBM traffic, memory-bound.
//
// R2 lesson: nt STORES diverge post-timing (banned). nt LOADS are safe.
// R4 lesson: per-block bias-from-b = 268 MB of L2 traffic (8x the bs variant)
//            -> keep the tiny bias_sum pre-kernel, read 16 KB bs per block.
// R1/R3/R4: three schedules all ~106 us -> schedule-insensitive; this round
//            attacks L2 pollution: evict-first (nontemporal) loads on the
//            single-use W rows, leaving L2 to the streaming write-allocate.

#define D_MODEL 4096
#define SHARDS 8
#define TPB 8  // tokens per block

typedef float f32x4 __attribute__((ext_vector_type(4)));

__global__ void bias_sum_kernel(const float* __restrict__ b, float* __restrict__ bs) {
    int d = blockIdx.x * blockDim.x + threadIdx.x;
    if (d < D_MODEL) {
        float s = 0.0f;
#pragma unroll
        for (int i = 0; i < SHARDS; ++i) s += b[i * D_MODEL + d];
        bs[d] = s;
    }
}

// 2048 blocks x 256 threads, 8 tokens each. Bias fragment registered once per
// block (16 KB from L2-resident bs). W rows read with nontemporal (evict-first)
// loads; plain coalesced stores.
__global__ __launch_bounds__(256) void gather_kernel(const int* __restrict__ tok,
                                                     const float* __restrict__ W,
                                                     const float* __restrict__ bs,
                                                     float* __restrict__ out,
                                                     int ntok) {
    const int tid = threadIdx.x;
    const int base = blockIdx.x * TPB;

    f32x4 bias[4];
    const f32x4* bs4 = reinterpret_cast<const f32x4*>(bs);
#pragma unroll
    for (int j = 0; j < 4; ++j) bias[j] = bs4[tid + j * 256];

    const f32x4* W4   = reinterpret_cast<const f32x4*>(W);
    f32x4*       out4 = reinterpret_cast<f32x4*>(out);

    for (int i = 0; i < TPB; ++i) {
        const int t = base + i;
        if (t >= ntok) break;
        const int row = tok[t];  // block-uniform scalar load
        const f32x4* wrow = W4 + (size_t)row * (D_MODEL / 4);

        f32x4 w[4];
#pragma unroll
        for (int j = 0; j < 4; ++j)
            w[j] = __builtin_nontemporal_load(&wrow[tid + j * 256]);

        f32x4* orow = out4 + (size_t)t * (D_MODEL / 4);
#pragma unroll
        for (int j = 0; j < 4; ++j)
            orow[tid + j * 256] = (w[j] + bias[j]) * 0.125f;
    }
}

extern "C" void kernel_launch(void* const* d_in, const int* in_sizes, int n_in,
                              void* d_out, int out_size, void* d_ws, size_t ws_size,
                              hipStream_t stream) {
    const int*   tok = (const int*)d_in[0];     // [16384]
    const float* W   = (const float*)d_in[1];   // [50400, 4096]
    const float* b   = (const float*)d_in[2];   // [8, 4096]
    float*       out = (float*)d_out;           // [16384, 4096]
    float*       bs  = (float*)d_ws;            // [4096] scratch

    const int ntok = in_sizes[0];               // 16384
    const int grid = (ntok + TPB - 1) / TPB;    // 2048

    bias_sum_kernel<<<(D_MODEL + 255) / 256, 256, 0, stream>>>(b, bs);
    gather_kernel<<<grid, 256, 0, stream>>>(tok, W, bs, out, ntok);
}